// Round 1
// baseline (424.417 us; speedup 1.0000x reference)
//
#include <hip/hip_runtime.h>

typedef unsigned long long u64;

// ws layout (floats):
#define OFF_A      0       // 510 floats: -0.5*||c||^2 per combo, level-major (off_L = 2^L-2)
#define OFF_DT     512     // dT[c*8+s] = w[r1[s]][c]-w[r0[s]][c]
#define OFF_V0T    1536    // v0T[c*8+s] = w[r0[s]][c]
#define OFF_BASET  2560    // baseT[(L-1)*128+c] = sum_{s<=L} w[r0[s]][c]
#define OFF_LACC   3584    // 8 float sse accumulators
#define OFF_IDX_BYTES 16384  // u64 packed indices per position (65536 * 8B)

__device__ __forceinline__ float warp_sum(float v) {
  #pragma unroll
  for (int off = 32; off > 0; off >>= 1) v += __shfl_down(v, off);
  return v;
}

// ---------------- Kernel A: build codebook tables (runs every launch; ws is re-poisoned) ---
__global__ __launch_bounds__(64) void build_tables(const float* __restrict__ w,
                                                   float* __restrict__ wsf) {
  const int r0[8] = {0, 3, 4, 5, 6, 7, 8, 9};
  int e = blockIdx.x;
  int t = threadIdx.x;
  if (e < 510) {
    int ep2 = e + 2;
    int L = 31 - __clz(ep2);        // level 1..8
    int i = ep2 - (1 << L);         // combo index, b1 = MSB
    float acc = 0.f;
    #pragma unroll
    for (int half = 0; half < 2; ++half) {
      int cc = t + half * 64;
      float v = 0.f;
      for (int s = 0; s < L; ++s) {
        int b = (i >> (L - 1 - s)) & 1;
        v += w[(r0[s] + b) * 128 + cc];
      }
      acc += v * v;
    }
    acc = warp_sum(acc);
    if (t == 0) wsf[OFF_A + e] = -0.5f * acc;
  } else {
    #pragma unroll
    for (int half = 0; half < 2; ++half) {
      int cc = t + half * 64;
      float basesum = 0.f;
      #pragma unroll
      for (int s = 0; s < 8; ++s) {
        float w0 = w[r0[s] * 128 + cc];
        float w1 = w[(r0[s] + 1) * 128 + cc];
        wsf[OFF_V0T + cc * 8 + s] = w0;
        wsf[OFF_DT + cc * 8 + s] = w1 - w0;
        basesum += w0;
        wsf[OFF_BASET + s * 128 + cc] = basesum;
      }
    }
    if (t < 8) wsf[OFF_LACC + t] = 0.f;
  }
}

// ---------------- Kernel B: per-position dots + per-level argmax + loss accumulation ------
template <int L>
__device__ __forceinline__ void search_level(const float* __restrict__ A,
                                             const float* T, const float* S,
                                             float& bestsc, int& bestidx) {
  const float* Al = A + ((1 << L) - 2);
  float bs = -3.4e38f;
  int bi = 0;
  #pragma unroll
  for (int i = 0; i < (1 << L); ++i) {
    float dot;
    if constexpr (L <= 4) {
      dot = T[i << (4 - L)];
    } else {
      dot = T[i >> (L - 4)] + S[(i & ((1 << (L - 4)) - 1)) << (8 - L)];
    }
    float sc = dot + Al[i];
    bool p = sc > bs;                 // strict > keeps lowest index on exact ties (argmin-first)
    bs = p ? sc : bs;
    bi = p ? i : bi;
  }
  bestsc = bs;
  bestidx = bi;
}

__global__ __launch_bounds__(256) void search_kernel(const float* __restrict__ in,
                                                     const float* __restrict__ tbl,
                                                     float* __restrict__ lacc,
                                                     u64* __restrict__ idxp) {
  int pos = blockIdx.x * 256 + threadIdx.x;
  int b = pos >> 12;
  int hw = pos & 4095;
  const float* xp = in + ((size_t)b << 19) + hw;   // input is (B,128,64,64): channel stride 4096
  const float* dT = tbl + OFF_DT;
  const float* v0T = tbl + OFF_V0T;

  float qq[8], uu[8];
  #pragma unroll
  for (int k = 0; k < 8; ++k) { qq[k] = 0.f; uu[k] = 0.f; }
  float xx = 0.f;
  #pragma unroll 4
  for (int c = 0; c < 128; ++c) {
    float x = xp[(size_t)c << 12];                 // coalesced across lanes (lane = hw)
    xx = fmaf(x, x, xx);
    #pragma unroll
    for (int k = 0; k < 8; ++k) {
      qq[k] = fmaf(x, dT[c * 8 + k], qq[k]);       // uniform -> s_load
      uu[k] = fmaf(x, v0T[c * 8 + k], uu[k]);
    }
  }

  // subset-sum tables: T over stages 1..4 (bit3<->stage1), S over stages 5..8 (bit3<->stage5)
  float T[16], S[16];
  #pragma unroll
  for (int h = 0; h < 16; ++h) {
    float tv = 0.f, sv = 0.f;
    if (h & 8) { tv += qq[0]; sv += qq[4]; }
    if (h & 4) { tv += qq[1]; sv += qq[5]; }
    if (h & 2) { tv += qq[2]; sv += qq[6]; }
    if (h & 1) { tv += qq[3]; sv += qq[7]; }
    T[h] = tv; S[h] = sv;
  }

  const float* A = tbl + OFF_A;
  float bsc[8];
  int bix[8];
  search_level<1>(A, T, S, bsc[0], bix[0]);
  search_level<2>(A, T, S, bsc[1], bix[1]);
  search_level<3>(A, T, S, bsc[2], bix[2]);
  search_level<4>(A, T, S, bsc[3], bix[3]);
  search_level<5>(A, T, S, bsc[4], bix[4]);
  search_level<6>(A, T, S, bsc[5], bix[5]);
  search_level<7>(A, T, S, bsc[6], bix[6]);
  search_level<8>(A, T, S, bsc[7], bix[7]);

  u64 pk = (u64)bix[0] | ((u64)bix[1] << 1) | ((u64)bix[2] << 3) | ((u64)bix[3] << 6) |
           ((u64)bix[4] << 10) | ((u64)bix[5] << 15) | ((u64)bix[6] << 21) |
           ((u64)bix[7] << 28);
  idxp[pos] = pk;

  float P0 = 0.f;
  #pragma unroll
  for (int l = 0; l < 8; ++l) {
    P0 += uu[l];                                   // x . base_L
    float sse = xx - 2.f * (P0 + bsc[l]);          // ||x - q||^2
    sse = warp_sum(sse);
    if ((threadIdx.x & 63) == 0) atomicAdd(&lacc[l], sse);
  }
}

// ---------------- Kernel C: reconstruct q and stream 268 MB output ------------------------
template <int LV>
__device__ __forceinline__ void write_level(const u64* __restrict__ idxp,
                                            const float* __restrict__ tbl,
                                            float* __restrict__ op, int pos) {
  const int SH[9] = {0, 0, 1, 3, 6, 10, 15, 21, 28};
  u64 pk = idxp[pos];
  int idx = (int)((pk >> SH[LV]) & ((1u << LV) - 1));
  float bf[LV];
  #pragma unroll
  for (int s = 0; s < LV; ++s) bf[s] = (float)((idx >> (LV - 1 - s)) & 1);
  const float* bt = tbl + OFF_BASET + (LV - 1) * 128;
  const float* dT = tbl + OFF_DT;
  #pragma unroll 4
  for (int c = 0; c < 128; ++c) {
    float qv = bt[c];                              // uniform scalar loads
    #pragma unroll
    for (int s = 0; s < LV; ++s) qv = fmaf(bf[s], dT[c * 8 + s], qv);
    op[(size_t)c << 12] = qv;                      // coalesced across lanes
  }
}

__global__ __launch_bounds__(256) void write_kernel(const float* __restrict__ tbl,
                                                    const u64* __restrict__ idxp,
                                                    float* __restrict__ out) {
  int blk = blockIdx.x;               // ((L*16 + bb)*16 + hb)
  int hb = blk & 15;
  int bb = (blk >> 4) & 15;
  int L = blk >> 8;                   // 0..7
  int hw = hb * 256 + threadIdx.x;
  int pos = (bb << 12) + hw;
  float* op = out + (((size_t)(L * 16 + bb)) << 19) + hw;
  switch (L) {
    case 0: write_level<1>(idxp, tbl, op, pos); break;
    case 1: write_level<2>(idxp, tbl, op, pos); break;
    case 2: write_level<3>(idxp, tbl, op, pos); break;
    case 3: write_level<4>(idxp, tbl, op, pos); break;
    case 4: write_level<5>(idxp, tbl, op, pos); break;
    case 5: write_level<6>(idxp, tbl, op, pos); break;
    case 6: write_level<7>(idxp, tbl, op, pos); break;
    case 7: write_level<8>(idxp, tbl, op, pos); break;
  }
  if (blk == 0 && threadIdx.x < 8) {
    const float CO[8] = {1.5f, 1.2f, 1.0f, 0.9f, 0.82f, 0.69f, 0.65f, 0.56f};
    const float* lacc = tbl + OFF_LACC;
    out[67108864ull + threadIdx.x] =
        (CO[threadIdx.x] + 0.4f) * lacc[threadIdx.x] * (1.0f / 8388608.0f);
  }
}

extern "C" void kernel_launch(void* const* d_in, const int* in_sizes, int n_in,
                              void* d_out, int out_size, void* d_ws, size_t ws_size,
                              hipStream_t stream) {
  const float* in = (const float*)d_in[0];   // (16,128,64,64) fp32
  const float* w  = (const float*)d_in[1];   // (256,128) fp32
  float* wsf = (float*)d_ws;
  u64* idxp = (u64*)((char*)d_ws + OFF_IDX_BYTES);
  float* out = (float*)d_out;

  build_tables<<<511, 64, 0, stream>>>(w, wsf);
  search_kernel<<<256, 256, 0, stream>>>(in, wsf, wsf + OFF_LACC, idxp);
  write_kernel<<<2048, 256, 0, stream>>>(wsf, idxp, out);
}

// Round 2
// 328.752 us; speedup vs baseline: 1.2910x; 1.2910x over previous
//
#include <hip/hip_runtime.h>

typedef unsigned long long u64;

// ws layout:
#define OFF_A      0        // 510 floats: -0.5*||c||^2 per combo, level-major (off_L = 2^L-2)
#define OFF_DT     512      // dT[c*8+s] = w[r1[s]][c]-w[r0[s]][c]
#define OFF_V0T    1536     // v0T[c*8+s] = w[r0[s]][c]
#define OFF_BASET  2560     // baseT[(L-1)*128+c] = sum_{s<=L} w[r0[s]][c]
#define OFF_IDX_BYTES 16384         // u64 packed indices per position (65536 * 8B)
#define OFF_PART_F    135168        // float offset of partial[8][256] block sums
                                    // = (16384 + 65536*8)/4

__device__ __forceinline__ float warp_sum(float v) {
  #pragma unroll
  for (int off = 32; off > 0; off >>= 1) v += __shfl_down(v, off);
  return v;
}

// ---------------- Kernel A: build codebook tables (ws re-poisoned every launch) -----------
__global__ __launch_bounds__(64) void build_tables(const float* __restrict__ w,
                                                   float* __restrict__ wsf) {
  const int r0[8] = {0, 3, 4, 5, 6, 7, 8, 9};
  int e = blockIdx.x;
  int t = threadIdx.x;
  if (e < 510) {
    int ep2 = e + 2;
    int L = 31 - __clz(ep2);        // level 1..8
    int i = ep2 - (1 << L);         // combo index, b1 = MSB
    float acc = 0.f;
    #pragma unroll
    for (int half = 0; half < 2; ++half) {
      int cc = t + half * 64;
      float v = 0.f;
      for (int s = 0; s < L; ++s) {
        int b = (i >> (L - 1 - s)) & 1;
        v += w[(r0[s] + b) * 128 + cc];
      }
      acc += v * v;
    }
    acc = warp_sum(acc);
    if (t == 0) wsf[OFF_A + e] = -0.5f * acc;
  } else {
    #pragma unroll
    for (int half = 0; half < 2; ++half) {
      int cc = t + half * 64;
      float basesum = 0.f;
      #pragma unroll
      for (int s = 0; s < 8; ++s) {
        float w0 = w[r0[s] * 128 + cc];
        float w1 = w[(r0[s] + 1) * 128 + cc];
        wsf[OFF_V0T + cc * 8 + s] = w0;
        wsf[OFF_DT + cc * 8 + s] = w1 - w0;
        basesum += w0;
        wsf[OFF_BASET + s * 128 + cc] = basesum;
      }
    }
  }
}

// ---------------- Guaranteed-unroll level search (all indices compile-time) ---------------
template <int L, int I, int N>
struct SU {
  static __device__ __forceinline__ void run(const float* __restrict__ Al,
                                             const float* T, const float* S,
                                             float& bs, int& bi) {
    float dot;
    if constexpr (L <= 4) {
      dot = T[I << (4 - L)];
    } else {
      dot = T[I >> (L - 4)] + S[(I & ((1 << (L - 4)) - 1)) << (8 - L)];
    }
    float sc = dot + Al[I];
    if (sc > bs) { bs = sc; bi = I; }   // strict > keeps lowest index on ties
    SU<L, I + 1, N>::run(Al, T, S, bs, bi);
  }
};
template <int L, int N>
struct SU<L, N, N> {
  static __device__ __forceinline__ void run(const float*, const float*, const float*,
                                             float&, int&) {}
};

template <int L>
__device__ __forceinline__ void search_level(const float* __restrict__ A,
                                             const float* T, const float* S,
                                             float& bestsc, int& bestidx) {
  const float* Al = A + ((1 << L) - 2);
  float bs = -3.4e38f;
  int bi = 0;
  SU<L, 0, (1 << L)>::run(Al, T, S, bs, bi);
  bestsc = bs;
  bestidx = bi;
}

// ---------------- Kernel B: dots + per-level argmax + block-level loss partials -----------
__global__ __launch_bounds__(256) void search_kernel(const float* __restrict__ in,
                                                     const float* __restrict__ tbl,
                                                     float* __restrict__ partial,
                                                     u64* __restrict__ idxp) {
  __shared__ float red[4][8];
  int pos = blockIdx.x * 256 + threadIdx.x;
  int b = pos >> 12;
  int hw = pos & 4095;
  const float* xp = in + ((size_t)b << 19) + hw;   // (B,128,64,64): channel stride 4096
  const float4* dT4 = (const float4*)(tbl + OFF_DT);
  const float4* v04 = (const float4*)(tbl + OFF_V0T);

  float qq[8], uu[8];
  #pragma unroll
  for (int k = 0; k < 8; ++k) { qq[k] = 0.f; uu[k] = 0.f; }
  float xx = 0.f;
  #pragma unroll 4
  for (int c = 0; c < 128; ++c) {
    float x = xp[(size_t)c << 12];                 // coalesced across lanes (lane = hw)
    float4 d0 = dT4[2 * c];
    float4 d1 = dT4[2 * c + 1];
    float4 u0 = v04[2 * c];
    float4 u1 = v04[2 * c + 1];
    xx = fmaf(x, x, xx);
    qq[0] = fmaf(x, d0.x, qq[0]); qq[1] = fmaf(x, d0.y, qq[1]);
    qq[2] = fmaf(x, d0.z, qq[2]); qq[3] = fmaf(x, d0.w, qq[3]);
    qq[4] = fmaf(x, d1.x, qq[4]); qq[5] = fmaf(x, d1.y, qq[5]);
    qq[6] = fmaf(x, d1.z, qq[6]); qq[7] = fmaf(x, d1.w, qq[7]);
    uu[0] = fmaf(x, u0.x, uu[0]); uu[1] = fmaf(x, u0.y, uu[1]);
    uu[2] = fmaf(x, u0.z, uu[2]); uu[3] = fmaf(x, u0.w, uu[3]);
    uu[4] = fmaf(x, u1.x, uu[4]); uu[5] = fmaf(x, u1.y, uu[5]);
    uu[6] = fmaf(x, u1.z, uu[6]); uu[7] = fmaf(x, u1.w, uu[7]);
  }

  // subset-sum tables: T over stages 1..4 (bit3<->stage1), S over stages 5..8 (bit3<->stage5)
  float T[16], S[16];
  #pragma unroll
  for (int h = 0; h < 16; ++h) {
    float tv = 0.f, sv = 0.f;
    if (h & 8) { tv += qq[0]; sv += qq[4]; }
    if (h & 4) { tv += qq[1]; sv += qq[5]; }
    if (h & 2) { tv += qq[2]; sv += qq[6]; }
    if (h & 1) { tv += qq[3]; sv += qq[7]; }
    T[h] = tv; S[h] = sv;
  }

  const float* A = tbl + OFF_A;
  float bsc[8];
  int bix[8];
  search_level<1>(A, T, S, bsc[0], bix[0]);
  search_level<2>(A, T, S, bsc[1], bix[1]);
  search_level<3>(A, T, S, bsc[2], bix[2]);
  search_level<4>(A, T, S, bsc[3], bix[3]);
  search_level<5>(A, T, S, bsc[4], bix[4]);
  search_level<6>(A, T, S, bsc[5], bix[5]);
  search_level<7>(A, T, S, bsc[6], bix[6]);
  search_level<8>(A, T, S, bsc[7], bix[7]);

  u64 pk = (u64)bix[0] | ((u64)bix[1] << 1) | ((u64)bix[2] << 3) | ((u64)bix[3] << 6) |
           ((u64)bix[4] << 10) | ((u64)bix[5] << 15) | ((u64)bix[6] << 21) |
           ((u64)bix[7] << 28);
  idxp[pos] = pk;

  // loss partials: wave reduce -> LDS -> one non-atomic store per level per block
  int wv = threadIdx.x >> 6;
  float P0 = 0.f;
  #pragma unroll
  for (int l = 0; l < 8; ++l) {
    P0 += uu[l];                                   // x . base_L
    float sse = xx - 2.f * (P0 + bsc[l]);          // ||x - q||^2
    sse = warp_sum(sse);
    if ((threadIdx.x & 63) == 0) red[wv][l] = sse;
  }
  __syncthreads();
  if (threadIdx.x < 8) {
    int l = threadIdx.x;
    partial[l * 256 + blockIdx.x] = red[0][l] + red[1][l] + red[2][l] + red[3][l];
  }
}

// ---------------- Kernel C: reconstruct q, stream 268 MB output, final loss reduce --------
template <int LV>
__device__ __forceinline__ void write_level(const u64* __restrict__ idxp,
                                            const float* __restrict__ tbl,
                                            float* __restrict__ op, int pos) {
  const int SH[9] = {0, 0, 1, 3, 6, 10, 15, 21, 28};
  u64 pk = idxp[pos];
  int idx = (int)((pk >> SH[LV]) & ((1u << LV) - 1));
  float bf[LV];
  #pragma unroll
  for (int s = 0; s < LV; ++s) bf[s] = (float)((idx >> (LV - 1 - s)) & 1);
  const float* bt = tbl + OFF_BASET + (LV - 1) * 128;
  const float4* dT4 = (const float4*)(tbl + OFF_DT);
  #pragma unroll 4
  for (int c = 0; c < 128; ++c) {
    float qv = bt[c];                              // uniform load
    float dv[8];
    float4 d0 = dT4[2 * c];
    dv[0] = d0.x; dv[1] = d0.y; dv[2] = d0.z; dv[3] = d0.w;
    if constexpr (LV > 4) {
      float4 d1 = dT4[2 * c + 1];
      dv[4] = d1.x; dv[5] = d1.y; dv[6] = d1.z; dv[7] = d1.w;
    }
    #pragma unroll
    for (int s = 0; s < LV; ++s) qv = fmaf(bf[s], dv[s], qv);
    op[(size_t)c << 12] = qv;                      // coalesced across lanes
  }
}

__global__ __launch_bounds__(256) void write_kernel(const float* __restrict__ tbl,
                                                    const u64* __restrict__ idxp,
                                                    float* __restrict__ out) {
  int blk = blockIdx.x;               // ((L*16 + bb)*16 + hb)
  int hb = blk & 15;
  int bb = (blk >> 4) & 15;
  int L = blk >> 8;                   // 0..7
  int hw = hb * 256 + threadIdx.x;
  int pos = (bb << 12) + hw;
  float* op = out + (((size_t)(L * 16 + bb)) << 19) + hw;
  switch (L) {
    case 0: write_level<1>(idxp, tbl, op, pos); break;
    case 1: write_level<2>(idxp, tbl, op, pos); break;
    case 2: write_level<3>(idxp, tbl, op, pos); break;
    case 3: write_level<4>(idxp, tbl, op, pos); break;
    case 4: write_level<5>(idxp, tbl, op, pos); break;
    case 5: write_level<6>(idxp, tbl, op, pos); break;
    case 6: write_level<7>(idxp, tbl, op, pos); break;
    case 7: write_level<8>(idxp, tbl, op, pos); break;
  }
  // deterministic final loss reduction, one wave, hidden under the store stream
  if (blk == 0 && threadIdx.x < 64) {
    const float CO[8] = {1.5f, 1.2f, 1.0f, 0.9f, 0.82f, 0.69f, 0.65f, 0.56f};
    const float* partial = tbl + OFF_PART_F;
    int t = threadIdx.x;
    int l = t >> 3;                   // level
    int j = t & 7;                    // sub-slot
    float s = 0.f;
    #pragma unroll 4
    for (int k = 0; k < 32; ++k) s += partial[l * 256 + j + k * 8];
    s += __shfl_down(s, 4);
    s += __shfl_down(s, 2);
    s += __shfl_down(s, 1);
    if (j == 0)
      out[67108864ull + l] = (CO[l] + 0.4f) * s * (1.0f / 8388608.0f);
  }
}

extern "C" void kernel_launch(void* const* d_in, const int* in_sizes, int n_in,
                              void* d_out, int out_size, void* d_ws, size_t ws_size,
                              hipStream_t stream) {
  const float* in = (const float*)d_in[0];   // (16,128,64,64) fp32
  const float* w  = (const float*)d_in[1];   // (256,128) fp32
  float* wsf = (float*)d_ws;
  u64* idxp = (u64*)((char*)d_ws + OFF_IDX_BYTES);
  float* partial = wsf + OFF_PART_F;
  float* out = (float*)d_out;

  build_tables<<<511, 64, 0, stream>>>(w, wsf);
  search_kernel<<<256, 256, 0, stream>>>(in, wsf, partial, idxp);
  write_kernel<<<2048, 256, 0, stream>>>(wsf, idxp, out);
}